// Round 12
// baseline (730.288 us; speedup 1.0000x reference)
//
#include <hip/hip_runtime.h>
#include <stdint.h>
#include <math.h>

#define NR 65536
#define NRH 32768
#define NC 256

__device__ __forceinline__ uint32_t f2key(float f) {
  uint32_t b = __float_as_uint(f);
  return (b & 0x80000000u) ? ~b : (b | 0x80000000u);
}

// Slab transpose: block handles 64 rows x ALL 256 cols. Reads each input line
// exactly once; every dst store instruction covers a FULL 128B line per column.
__global__ __launch_bounds__(256) void k_transpose_key(const float* __restrict__ X,
                                                       const float* __restrict__ Xh,
                                                       uint32_t* __restrict__ outX,
                                                       uint32_t* __restrict__ outH) {
  __shared__ uint32_t tile[64][260];
  const float* in = blockIdx.z ? Xh : X;
  uint32_t* out = blockIdx.z ? outH : outX;
  const int t = threadIdx.x;
  const int r0 = blockIdx.x * 64;
#pragma unroll
  for (int i = 0; i < 16; ++i) {
    int row = i * 4 + (t >> 6);
    const float4* rp = (const float4*)(in + (size_t)(r0 + row) * NC);
    float4 v = rp[t & 63];
    uint4 k4;
    k4.x = f2key(v.x); k4.y = f2key(v.y); k4.z = f2key(v.z); k4.w = f2key(v.w);
    *(uint4*)&tile[row][(t & 63) * 4] = k4;
  }
  __syncthreads();
  const int c0 = t >> 3;       // 0..31
  const int rb = 4 * (t & 7);  // 0,4,...,28
#pragma unroll
  for (int cc = 0; cc < 8; ++cc) {
    int c = cc * 32 + c0;
#pragma unroll
    for (int h = 0; h < 2; ++h) {
      int r = 32 * h + rb;
      uint4 o;
      o.x = tile[r][c]; o.y = tile[r + 1][c];
      o.z = tile[r + 2][c]; o.w = tile[r + 3][c];
      *(uint4*)(out + (size_t)c * NR + r0 + r) = o;
    }
  }
}

// Mixed-role grid. Blocks 0..511: per-(arr,col) byte-0 full histogram (8-way
// LDS split) + half0 byte-0 histogram; zero the 6 chain planes for this
// (arr,col). Blocks 512..768: write the ln table (f64-rounded).
// Planes (u32, stride B=65536 per [arr][col][bin] group):
//   FH0[2B]  full byte-0 hists        HZ[2B]  half0 byte-0 hists
//   FFH[3][2B] chained full hists     HH[3][2B] chained half0 hists
__global__ __launch_bounds__(1024) void k_allhist(const uint32_t* __restrict__ kX,
                                                  const uint32_t* __restrict__ kH,
                                                  uint32_t* __restrict__ FH0,
                                                  uint32_t* __restrict__ HZ,
                                                  uint32_t* __restrict__ FFH,
                                                  uint32_t* __restrict__ HH,
                                                  float2* __restrict__ tab) {
  const int bid = blockIdx.x, t = threadIdx.x;
  if (bid >= 512) {  // table role
    int v = (bid - 512) * 256 + (t & 255);
    if (t < 256 && v <= 65536) {
      float2 p;
      p.x = (float)log((double)(v + 1));
      p.y = (float)log((double)(65537 - v));
      tab[v] = p;
    }
    return;
  }
  __shared__ uint32_t h[8][256];  // byte-0 only, 8-way split
  __shared__ uint32_t hz[2][256];
  const int arr = bid >> 8, col = bid & 255;
  const uint32_t* src = (arr ? kH : kX) + (size_t)col * NR;
  for (int i = t; i < 8 * 256; i += 1024) ((uint32_t*)h)[i] = 0;
  if (t < 512) ((uint32_t*)hz)[t] = 0;
  if (t < 256) {
    size_t sl = ((size_t)arr * 256 + col) * 256 + t;
#pragma unroll
    for (int p = 0; p < 3; ++p) {
      FFH[(size_t)p * 2 * 65536 + sl] = 0;
      HH[(size_t)p * 2 * 65536 + sl] = 0;
    }
  }
  __syncthreads();
  const int cp = t >> 7;
  const uint4* s4 = (const uint4*)src;
  for (int i = t; i < NR / 4; i += 1024) {
    uint4 v = s4[i];
    const bool inH0 = i < (NRH / 4);
    uint32_t a[4] = {v.x, v.y, v.z, v.w};
#pragma unroll
    for (int e = 0; e < 4; ++e) {
      uint32_t x = a[e] & 255u;
      atomicAdd(&h[cp][x], 1u);
      if (inH0) atomicAdd(&hz[cp & 1][x], 1u);
    }
  }
  __syncthreads();
  if (t < 256) {
    uint32_t s = 0;
#pragma unroll
    for (int c = 0; c < 8; ++c) s += h[c][t];
    size_t sl = ((size_t)arr * 256 + col) * 256 + t;
    FH0[sl] = s;
    HZ[sl] = hz[0][t] + hz[1][t];
  }
}

// Stable 8-bit counting-sort pass; one 512-thread block per (array,col,HALF).
// CHUNK=2048, distributed megaphase. half1 offsets = full-CDF + hin[d].
// Out-phase chains BOTH next-pass hists: fout (full, all keys) and hout
// (half0, keys landing at g<NRH). Last pass: fout=hout=null.
__global__ __launch_bounds__(512, 8) void k_radix_pass(
    const uint32_t* __restrict__ s0, uint32_t* __restrict__ d0,
    const uint32_t* __restrict__ s1, uint32_t* __restrict__ d1, int shift,
    const uint32_t* __restrict__ FHp, const uint32_t* __restrict__ HINp,
    uint32_t* __restrict__ FOUTp, uint32_t* __restrict__ HOUTp) {
  const int bid = blockIdx.x;
  const int arr = bid >> 9, col = (bid >> 1) & 255, half = bid & 1;
  const uint32_t* src = (arr ? s1 : s0) + (size_t)col * NR + (size_t)half * NRH;
  uint32_t* dst = (arr ? d1 : d0) + (size_t)col * NR;  // column-global positions
  const size_t sl = ((size_t)arr * 256 + col) * 256;
  const uint32_t* fh = FHp + sl;
  const uint32_t* hin = HINp + sl;
  uint32_t* fout = FOUTp ? FOUTp + sl : (uint32_t*)0;
  uint32_t* hout = HOUTp ? HOUTp + sl : (uint32_t*)0;

  __shared__ uint32_t waveCnt[8][256];  // counts during ranking, offsets after
  __shared__ uint32_t stage[2048];
  __shared__ uint32_t runoffP[2][256];
  __shared__ uint32_t chunkStart[256];
  __shared__ uint32_t chunkTot[256];
  __shared__ uint32_t nh[8][256];  // [0..3]: full chain, [4..7]: half0 chain

  const int t = threadIdx.x;
  const int lane = t & 63, w = t >> 6;  // 8 waves
  const uint64_t ltm = (1ULL << lane) - 1ULL;

  for (int i = t; i < 8 * 256; i += 512) ((uint32_t*)nh)[i] = 0;
  if (t < 256) runoffP[0][t] = fh[t];
  __syncthreads();
  if (w == 0) {  // excl scan of full-column hist; +hin for half 1
    uint32_t carry = 0;
#pragma unroll
    for (int q = 0; q < 4; ++q) {
      int d = lane + 64 * q;
      uint32_t v = runoffP[0][d];
      uint32_t inc = v;
      for (int off = 1; off < 64; off <<= 1) {
        uint32_t nn = __shfl_up(inc, off);
        if (lane >= off) inc += nn;
      }
      runoffP[0][d] = carry + inc - v + (half ? hin[d] : 0u);
      carry += __shfl(inc, 63);
    }
  }
  __syncthreads();

  int par = 0;
  uint32_t key[4];
#pragma unroll
  for (int k = 0; k < 4; ++k) key[k] = src[256 * w + 64 * k + lane];

  for (int cb = 0; cb < NRH; cb += 2048) {
    // zero own count row (wave-local; only this wave reads it until B1)
#pragma unroll
    for (int z = 0; z < 4; ++z) waveCnt[w][lane + 64 * z] = 0;
    __builtin_amdgcn_wave_barrier();
    uint32_t nxt[4];
    const bool more = (cb + 2048) < NRH;
    if (more) {
#pragma unroll
      for (int k = 0; k < 4; ++k)
        nxt[k] = src[cb + 2048 + 256 * w + 64 * k + lane];
    }
    // wave-local stable ranking (element id = cb + 256w + 64k + lane)
    uint32_t rnk[4];
#pragma unroll
    for (int k = 0; k < 4; ++k) {
      uint32_t d = (key[k] >> shift) & 255u;
      uint32_t pre = waveCnt[w][d];
      uint64_t m = ~0ULL;
#pragma unroll
      for (int b = 0; b < 8; ++b) {
        uint64_t bb = __ballot((d >> b) & 1u);
        m &= ((d >> b) & 1u) ? bb : ~bb;
      }
      uint32_t lower = (uint32_t)__popcll(m & ltm);
      rnk[k] = pre + lower;
      if (lower == 0) waveCnt[w][d] = pre + (uint32_t)__popcll(m);
      __builtin_amdgcn_wave_barrier();
    }
    __syncthreads();  // B1: ranking done (also fences prev out-phase)
    if (t < 256) {    // phase A (parallel): counts->offsets, totals, runoff
      int d = t;
      uint32_t run = 0;
#pragma unroll
      for (int ww = 0; ww < 8; ++ww) {
        uint32_t tmp = waveCnt[ww][d];
        waveCnt[ww][d] = run;  // becomes per-wave offset
        run += tmp;
      }
      runoffP[par ^ 1][d] = runoffP[par][d] + run;
      chunkTot[d] = run;
    }
    __syncthreads();  // B1.5: totals ready
    if (w == 0) {     // phase B (short): 256-bin exclusive scan
      uint32_t carry = 0;
#pragma unroll
      for (int q = 0; q < 4; ++q) {
        int d = lane + 64 * q;
        uint32_t run = chunkTot[d];
        uint32_t inc = run;
        for (int off = 1; off < 64; off <<= 1) {
          uint32_t nn = __shfl_up(inc, off);
          if (lane >= off) inc += nn;
        }
        chunkStart[d] = carry + inc - run;
        carry += __shfl(inc, 63);
      }
    }
    __syncthreads();  // B2: offsets/chunkStart ready
#pragma unroll
    for (int k = 0; k < 4; ++k) {
      uint32_t d = (key[k] >> shift) & 255u;
      stage[chunkStart[d] + waveCnt[w][d] + rnk[k]] = key[k];
    }
    __syncthreads();  // B3: staged digit-sorted
#pragma unroll
    for (int k = 0; k < 4; ++k) {
      int p = t + 512 * k;  // consecutive lanes -> consecutive dst
      uint32_t kk = stage[p];
      uint32_t d = (kk >> shift) & 255u;
      uint32_t g = runoffP[par][d] + (uint32_t)p - chunkStart[d];
      dst[g] = kk;
      if (fout) {
        uint32_t d2 = (kk >> (shift + 8)) & 255u;
        atomicAdd(&nh[w & 3][d2], 1u);
        if (g < NRH) atomicAdd(&nh[4 + (w & 3)][d2], 1u);
      }
    }
    par ^= 1;
    if (more) {
#pragma unroll
      for (int k = 0; k < 4; ++k) key[k] = nxt[k];
    }
  }
  if (fout) {
    __syncthreads();
    if (t < 256) {
      atomicAdd(&fout[t], nh[0][t] + nh[1][t] + nh[2][t] + nh[3][t]);
      uint32_t s = nh[4][t] + nh[5][t] + nh[6][t] + nh[7][t];
      if (s) atomicAdd(&hout[t], s);
    }
  }
}

// LDS-staged merge + AD accumulation via ln-table gathers; quarter-columns.
// Seed found in-block (redundant binary search, broadcast loads).
__global__ __launch_bounds__(1024, 8) void k_ad_accum(const uint32_t* __restrict__ xs,
                                                      const uint32_t* __restrict__ xh,
                                                      const float2* __restrict__ tab,
                                                      double* __restrict__ colsum) {
  constexpr int BCH = 4096, CAPA = 5120;
  __shared__ uint32_t ldsB[BCH];
  __shared__ uint32_t ldsA[CAPA];
  __shared__ int sh_jnext;
  __shared__ double red16[16];
  const int bid = blockIdx.x, col = bid >> 2, q = bid & 3, t = threadIdx.x;
  const int lane = t & 63, w = t >> 6;
  const uint32_t* A = xs + (size_t)col * NR;
  const uint32_t* B = xh + (size_t)col * NR;
  const int base0 = q * (NR / 4);
  int jb;  // seed: #{A <= B[base0]}
  {
    uint32_t v0 = B[base0];
    int lo = 0, hi = NR;
    while (lo < hi) {
      int mid = (lo + hi) >> 1;
      if (A[mid] <= v0) lo = mid + 1; else hi = mid;
    }
    jb = lo;
  }
  double acc = 0.0;
  for (int r = 0; r < (NR / 4) / BCH; ++r) {
    int base = base0 + r * BCH;
#pragma unroll
    for (int k = 0; k < 4; ++k) ldsB[t + 1024 * k] = B[base + t + 1024 * k];
    int avail = min(CAPA, NR - jb);
    for (int i = t; i < avail; i += 1024) ldsA[i] = A[jb + i];
    __syncthreads();
    uint4 bv = ((const uint4*)ldsB)[t];
    uint32_t be[4] = {bv.x, bv.y, bv.z, bv.w};
    int lo = 0, hi = avail;
    while (lo < hi) {
      int mid = (lo + hi) >> 1;
      if (ldsA[mid] <= be[0]) lo = mid + 1; else hi = mid;
    }
    int j = lo;
    long jg = -1;  // rare window-overflow fallback (global walk)
#pragma unroll
    for (int k = 0; k < 4; ++k) {
      uint32_t v = be[k];
      if (jg < 0) {
        while (j < avail && ldsA[j] <= v) ++j;
        if (j == avail && jb + avail < NR) jg = jb + avail;
      }
      if (jg >= 0) {
        while (jg < NR && A[jg] <= v) ++jg;
      }
      int cnt = (jg >= 0) ? (int)jg : jb + j;
      int i = base + 4 * t + k;
      float2 p = tab[cnt];  // {ln(cnt+1), ln(65537-cnt)}
      acc += (double)((float)(2 * i + 1) * p.x + (float)(2 * NR - 1 - 2 * i) * p.y);
    }
    if (t == 1023) sh_jnext = (jg >= 0) ? (int)jg : jb + j;
    __syncthreads();
    jb = sh_jnext;
  }
  for (int off = 32; off > 0; off >>= 1) acc += __shfl_down(acc, off);
  if (lane == 0) red16[w] = acc;
  __syncthreads();
  if (t == 0) {
    double s = 0.0;
#pragma unroll
    for (int i = 0; i < 16; ++i) s += red16[i];
    colsum[bid] = s;
  }
}

__global__ __launch_bounds__(1024) void k_final(const double* __restrict__ colsum,
                                                float* __restrict__ out) {
  __shared__ double red16[16];
  int t = threadIdx.x, lane = t & 63, w = t >> 6;
  double v = colsum[t];
  for (int off = 32; off > 0; off >>= 1) v += __shfl_down(v, off);
  if (lane == 0) red16[w] = v;
  __syncthreads();
  if (t == 0) {
    double total = 0.0;
#pragma unroll
    for (int i = 0; i < 16; ++i) total += red16[i];
    double dist = -total / ((double)NR * (double)NC)
                  + 2.0 * (double)NR * log(65538.0) - (double)NR;
    out[0] = (float)dist;
  }
}

extern "C" void kernel_launch(void* const* d_in, const int* in_sizes, int n_in,
                              void* d_out, int out_size, void* d_ws, size_t ws_size,
                              hipStream_t stream) {
  const float* X = (const float*)d_in[0];
  const float* Xh = (const float*)d_in[1];
  float* out = (float*)d_out;

  const size_t NEL = (size_t)NC * NR;  // 64 MiB per buffer
  const size_t B = 65536;              // one [arr-group] plane: 256 cols x 256 bins
  uint32_t* P0 = (uint32_t*)d_ws;
  uint32_t* P1 = P0 + NEL;
  uint32_t* P2 = P1 + NEL;
  double* colsum = (double*)P1;  // carved from dead P1 after sorts (8 KB)

  dim3 tg(NR / 64, 1, 2);
  k_transpose_key<<<tg, 256, 0, stream>>>(X, Xh, P0, P2);

  // hist region: FH0 2B + HZ 2B + FFH 6B + HH 6B = 16B u32 = 4 MiB, then tab
  const size_t HSP = 16 * B;
  const size_t TABW = 65537 * 2;  // floats
  uint32_t* nul = nullptr;
  bool fused = ws_size >= (4 * NEL + HSP + TABW) * sizeof(uint32_t);
  if (fused) {
    uint32_t* P3 = P2 + NEL;
    uint32_t* FH0 = P3 + NEL;
    uint32_t* HZ = FH0 + 2 * B;
    uint32_t* FFH = HZ + 2 * B;
    uint32_t* HH = FFH + 6 * B;
    float2* tab = (float2*)(HH + 6 * B);
    k_allhist<<<769, 1024, 0, stream>>>(P0, P2, FH0, HZ, FFH, HH, tab);
    k_radix_pass<<<1024, 512, 0, stream>>>(P0, P1, P2, P3, 0,  FH0,         HZ,         FFH,         HH);
    k_radix_pass<<<1024, 512, 0, stream>>>(P1, P0, P3, P2, 8,  FFH,         HH,         FFH + 2 * B, HH + 2 * B);
    k_radix_pass<<<1024, 512, 0, stream>>>(P0, P1, P2, P3, 16, FFH + 2 * B, HH + 2 * B, FFH + 4 * B, HH + 4 * B);
    k_radix_pass<<<1024, 512, 0, stream>>>(P1, P0, P3, P2, 24, FFH + 4 * B, HH + 4 * B, nul,         nul);
    k_ad_accum<<<1024, 1024, 0, stream>>>(P0, P2, tab, colsum);
  } else {
    // sequential 3-buffer fallback: per-array passes, grid 512 (arr folds to 0)
    uint32_t* FH0 = P2 + NEL;
    uint32_t* HZ = FH0 + 2 * B;
    uint32_t* FFH = HZ + 2 * B;
    uint32_t* HH = FFH + 6 * B;
    float2* tab = (float2*)(HH + 6 * B);
    k_allhist<<<769, 1024, 0, stream>>>(P0, P2, FH0, HZ, FFH, HH, tab);
    for (int arr = 0; arr < 2; ++arr) {
      uint32_t* a = arr ? P2 : P0;
      size_t ao = (size_t)arr * B;
      k_radix_pass<<<512, 512, 0, stream>>>(a,  P1, a,  P1, 0,  FH0 + ao,         HZ + ao,         FFH + ao,         HH + ao);
      k_radix_pass<<<512, 512, 0, stream>>>(P1, a,  P1, a,  8,  FFH + ao,         HH + ao,         FFH + 2 * B + ao, HH + 2 * B + ao);
      k_radix_pass<<<512, 512, 0, stream>>>(a,  P1, a,  P1, 16, FFH + 2 * B + ao, HH + 2 * B + ao, FFH + 4 * B + ao, HH + 4 * B + ao);
      k_radix_pass<<<512, 512, 0, stream>>>(P1, a,  P1, a,  24, FFH + 4 * B + ao, HH + 4 * B + ao, nul,              nul);
    }
    k_ad_accum<<<1024, 1024, 0, stream>>>(P0, P2, tab, colsum);
  }

  k_final<<<1, 1024, 0, stream>>>(colsum, out);
}

// Round 13
// 722.032 us; speedup vs baseline: 1.0114x; 1.0114x over previous
//
#include <hip/hip_runtime.h>
#include <stdint.h>
#include <math.h>

#define NR 65536
#define NRH 32768
#define NC 256

__device__ __forceinline__ uint32_t f2key(float f) {
  uint32_t b = __float_as_uint(f);
  return (b & 0x80000000u) ? ~b : (b | 0x80000000u);
}

// Slab transpose: block handles 64 rows x ALL 256 cols. Reads each input line
// exactly once; every dst store instruction covers a FULL 128B line per column.
__global__ __launch_bounds__(256) void k_transpose_key(const float* __restrict__ X,
                                                       const float* __restrict__ Xh,
                                                       uint32_t* __restrict__ outX,
                                                       uint32_t* __restrict__ outH) {
  __shared__ uint32_t tile[64][260];
  const float* in = blockIdx.z ? Xh : X;
  uint32_t* out = blockIdx.z ? outH : outX;
  const int t = threadIdx.x;
  const int r0 = blockIdx.x * 64;
#pragma unroll
  for (int i = 0; i < 16; ++i) {
    int row = i * 4 + (t >> 6);
    const float4* rp = (const float4*)(in + (size_t)(r0 + row) * NC);
    float4 v = rp[t & 63];
    uint4 k4;
    k4.x = f2key(v.x); k4.y = f2key(v.y); k4.z = f2key(v.z); k4.w = f2key(v.w);
    *(uint4*)&tile[row][(t & 63) * 4] = k4;
  }
  __syncthreads();
  const int c0 = t >> 3;       // 0..31
  const int rb = 4 * (t & 7);  // 0,4,...,28
#pragma unroll
  for (int cc = 0; cc < 8; ++cc) {
    int c = cc * 32 + c0;
#pragma unroll
    for (int h = 0; h < 2; ++h) {
      int r = 32 * h + rb;
      uint4 o;
      o.x = tile[r][c]; o.y = tile[r + 1][c];
      o.z = tile[r + 2][c]; o.w = tile[r + 3][c];
      *(uint4*)(out + (size_t)c * NR + r0 + r) = o;
    }
  }
}

// Mixed-role grid. Blocks 0..511: per-(arr,col) FULL histograms for all 4
// passes (8-way LDS sub-copies) + half0 byte-0 histogram; zero the 3 HH
// chain planes. Blocks 512..768: write the ln table (f64-rounded).
// FH: [pass4][arr2][col][bin] ; HZ: [arr2][col][bin] ; HH: [3][arr2][col][bin]
__global__ __launch_bounds__(1024) void k_allhist(const uint32_t* __restrict__ kX,
                                                  const uint32_t* __restrict__ kH,
                                                  uint32_t* __restrict__ FH,
                                                  uint32_t* __restrict__ HZ,
                                                  uint32_t* __restrict__ HH,
                                                  float2* __restrict__ tab) {
  const int bid = blockIdx.x, t = threadIdx.x;
  if (bid >= 512) {  // table role
    int v = (bid - 512) * 256 + (t & 255);
    if (t < 256 && v <= 65536) {
      float2 p;
      p.x = (float)log((double)(v + 1));
      p.y = (float)log((double)(65537 - v));
      tab[v] = p;
    }
    return;
  }
  __shared__ uint32_t h[8][4][256];  // 32 KB
  __shared__ uint32_t hz[2][256];
  const int arr = bid >> 8, col = bid & 255;
  const uint32_t* src = (arr ? kH : kX) + (size_t)col * NR;
  for (int i = t; i < 8 * 4 * 256; i += 1024) ((uint32_t*)h)[i] = 0;
  if (t < 512) ((uint32_t*)hz)[t] = 0;
  if (t < 256) {
    size_t sl = ((size_t)arr * 256 + col) * 256 + t;
#pragma unroll
    for (int p = 0; p < 3; ++p) HH[(size_t)p * 2 * 65536 + sl] = 0;
  }
  __syncthreads();
  const int cp = t >> 7;
  const uint4* s4 = (const uint4*)src;
  for (int i = t; i < NR / 4; i += 1024) {
    uint4 v = s4[i];
    const bool inH0 = i < (NRH / 4);
    uint32_t a[4] = {v.x, v.y, v.z, v.w};
#pragma unroll
    for (int e = 0; e < 4; ++e) {
      uint32_t x = a[e];
      atomicAdd(&h[cp][0][x & 255u], 1u);
      atomicAdd(&h[cp][1][(x >> 8) & 255u], 1u);
      atomicAdd(&h[cp][2][(x >> 16) & 255u], 1u);
      atomicAdd(&h[cp][3][x >> 24], 1u);
      if (inH0) atomicAdd(&hz[cp & 1][x & 255u], 1u);
    }
  }
  __syncthreads();
  if (t < 256) {
    size_t sl = ((size_t)arr * 256 + col) * 256 + t;
#pragma unroll
    for (int p = 0; p < 4; ++p) {
      uint32_t s = 0;
#pragma unroll
      for (int c = 0; c < 8; ++c) s += h[c][p][t];
      FH[(size_t)p * 2 * 65536 + sl] = s;
    }
    HZ[sl] = hz[0][t] + hz[1][t];
  }
}

// Stable 8-bit counting-sort pass; one 512-thread block per (array,col,HALF).
// CHUNK=2048 (4 keys/thread). Distributed megaphase. half1 offsets =
// full-CDF + hin[d]; out-phase accumulates next pass's half0 hist (hout).
__global__ __launch_bounds__(512, 8) void k_radix_pass(
    const uint32_t* __restrict__ s0, uint32_t* __restrict__ d0,
    const uint32_t* __restrict__ s1, uint32_t* __restrict__ d1, int shift,
    const uint32_t* __restrict__ FHp, const uint32_t* __restrict__ HINp,
    uint32_t* __restrict__ HOUTp) {
  const int bid = blockIdx.x;
  const int arr = bid >> 9, col = (bid >> 1) & 255, half = bid & 1;
  const uint32_t* src = (arr ? s1 : s0) + (size_t)col * NR + (size_t)half * NRH;
  uint32_t* dst = (arr ? d1 : d0) + (size_t)col * NR;  // column-global positions
  const size_t sl = ((size_t)arr * 256 + col) * 256;
  const uint32_t* fh = FHp + sl;
  const uint32_t* hin = HINp + sl;
  uint32_t* hout = HOUTp ? HOUTp + sl : (uint32_t*)0;

  __shared__ uint32_t waveCnt[8][256];  // counts during ranking, offsets after
  __shared__ uint32_t stage[2048];
  __shared__ uint32_t runoffP[2][256];
  __shared__ uint32_t chunkStart[256];
  __shared__ uint32_t chunkTot[256];
  __shared__ uint32_t nh[4][256];

  const int t = threadIdx.x;
  const int lane = t & 63, w = t >> 6;  // 8 waves
  const uint64_t ltm = (1ULL << lane) - 1ULL;

  for (int i = t; i < 4 * 256; i += 512) ((uint32_t*)nh)[i] = 0;
  if (t < 256) runoffP[0][t] = fh[t];
  __syncthreads();
  if (w == 0) {  // excl scan of full-column hist; +hin for half 1
    uint32_t carry = 0;
#pragma unroll
    for (int q = 0; q < 4; ++q) {
      int d = lane + 64 * q;
      uint32_t v = runoffP[0][d];
      uint32_t inc = v;
      for (int off = 1; off < 64; off <<= 1) {
        uint32_t nn = __shfl_up(inc, off);
        if (lane >= off) inc += nn;
      }
      runoffP[0][d] = carry + inc - v + (half ? hin[d] : 0u);
      carry += __shfl(inc, 63);
    }
  }
  __syncthreads();

  int par = 0;
  uint32_t key[4];
#pragma unroll
  for (int k = 0; k < 4; ++k) key[k] = src[256 * w + 64 * k + lane];

  for (int cb = 0; cb < NRH; cb += 2048) {
    // zero own count row (wave-local; only this wave reads it until B1)
#pragma unroll
    for (int z = 0; z < 4; ++z) waveCnt[w][lane + 64 * z] = 0;
    __builtin_amdgcn_wave_barrier();
    uint32_t nxt[4];
    const bool more = (cb + 2048) < NRH;
    if (more) {
#pragma unroll
      for (int k = 0; k < 4; ++k)
        nxt[k] = src[cb + 2048 + 256 * w + 64 * k + lane];
    }
    // wave-local stable ranking (element id = cb + 256w + 64k + lane)
    uint32_t rnk[4];
#pragma unroll
    for (int k = 0; k < 4; ++k) {
      uint32_t d = (key[k] >> shift) & 255u;
      uint32_t pre = waveCnt[w][d];
      uint64_t m = ~0ULL;
#pragma unroll
      for (int b = 0; b < 8; ++b) {
        uint64_t bb = __ballot((d >> b) & 1u);
        m &= ((d >> b) & 1u) ? bb : ~bb;
      }
      uint32_t lower = (uint32_t)__popcll(m & ltm);
      rnk[k] = pre + lower;
      if (lower == 0) waveCnt[w][d] = pre + (uint32_t)__popcll(m);
      __builtin_amdgcn_wave_barrier();
    }
    __syncthreads();  // B1: ranking done (also fences prev out-phase)
    if (t < 256) {    // phase A (parallel): counts->offsets, totals, runoff
      int d = t;
      uint32_t run = 0;
#pragma unroll
      for (int ww = 0; ww < 8; ++ww) {
        uint32_t tmp = waveCnt[ww][d];
        waveCnt[ww][d] = run;  // becomes per-wave offset
        run += tmp;
      }
      runoffP[par ^ 1][d] = runoffP[par][d] + run;
      chunkTot[d] = run;
    }
    __syncthreads();  // B1.5: totals ready
    if (w == 0) {     // phase B (short): 256-bin exclusive scan
      uint32_t carry = 0;
#pragma unroll
      for (int q = 0; q < 4; ++q) {
        int d = lane + 64 * q;
        uint32_t run = chunkTot[d];
        uint32_t inc = run;
        for (int off = 1; off < 64; off <<= 1) {
          uint32_t nn = __shfl_up(inc, off);
          if (lane >= off) inc += nn;
        }
        chunkStart[d] = carry + inc - run;
        carry += __shfl(inc, 63);
      }
    }
    __syncthreads();  // B2: offsets/chunkStart ready
#pragma unroll
    for (int k = 0; k < 4; ++k) {
      uint32_t d = (key[k] >> shift) & 255u;
      stage[chunkStart[d] + waveCnt[w][d] + rnk[k]] = key[k];
    }
    __syncthreads();  // B3: staged digit-sorted
#pragma unroll
    for (int k = 0; k < 4; ++k) {
      int p = t + 512 * k;  // consecutive lanes -> consecutive dst
      uint32_t kk = stage[p];
      uint32_t d = (kk >> shift) & 255u;
      uint32_t g = runoffP[par][d] + (uint32_t)p - chunkStart[d];
      dst[g] = kk;
      if (hout && g < NRH)
        atomicAdd(&nh[w & 3][(kk >> (shift + 8)) & 255u], 1u);
    }
    par ^= 1;
    if (more) {
#pragma unroll
      for (int k = 0; k < 4; ++k) key[k] = nxt[k];
    }
  }
  if (hout) {
    __syncthreads();
    if (t < 256) {
      uint32_t s = nh[0][t] + nh[1][t] + nh[2][t] + nh[3][t];
      if (s) atomicAdd(&hout[t], s);
    }
  }
}

// LDS-staged merge + AD accumulation via ln-table gathers; quarter-columns.
// Seed found in-block (redundant binary search, broadcast loads).
__global__ __launch_bounds__(1024, 8) void k_ad_accum(const uint32_t* __restrict__ xs,
                                                      const uint32_t* __restrict__ xh,
                                                      const float2* __restrict__ tab,
                                                      double* __restrict__ colsum) {
  constexpr int BCH = 4096, CAPA = 5120;
  __shared__ uint32_t ldsB[BCH];
  __shared__ uint32_t ldsA[CAPA];
  __shared__ int sh_jnext;
  __shared__ double red16[16];
  const int bid = blockIdx.x, col = bid >> 2, q = bid & 3, t = threadIdx.x;
  const int lane = t & 63, w = t >> 6;
  const uint32_t* A = xs + (size_t)col * NR;
  const uint32_t* B = xh + (size_t)col * NR;
  const int base0 = q * (NR / 4);
  int jb;  // seed: #{A <= B[base0]}
  {
    uint32_t v0 = B[base0];
    int lo = 0, hi = NR;
    while (lo < hi) {
      int mid = (lo + hi) >> 1;
      if (A[mid] <= v0) lo = mid + 1; else hi = mid;
    }
    jb = lo;
  }
  double acc = 0.0;
  for (int r = 0; r < (NR / 4) / BCH; ++r) {
    int base = base0 + r * BCH;
#pragma unroll
    for (int k = 0; k < 4; ++k) ldsB[t + 1024 * k] = B[base + t + 1024 * k];
    int avail = min(CAPA, NR - jb);
    for (int i = t; i < avail; i += 1024) ldsA[i] = A[jb + i];
    __syncthreads();
    uint4 bv = ((const uint4*)ldsB)[t];
    uint32_t be[4] = {bv.x, bv.y, bv.z, bv.w};
    int lo = 0, hi = avail;
    while (lo < hi) {
      int mid = (lo + hi) >> 1;
      if (ldsA[mid] <= be[0]) lo = mid + 1; else hi = mid;
    }
    int j = lo;
    long jg = -1;  // rare window-overflow fallback (global walk)
#pragma unroll
    for (int k = 0; k < 4; ++k) {
      uint32_t v = be[k];
      if (jg < 0) {
        while (j < avail && ldsA[j] <= v) ++j;
        if (j == avail && jb + avail < NR) jg = jb + avail;
      }
      if (jg >= 0) {
        while (jg < NR && A[jg] <= v) ++jg;
      }
      int cnt = (jg >= 0) ? (int)jg : jb + j;
      int i = base + 4 * t + k;
      float2 p = tab[cnt];  // {ln(cnt+1), ln(65537-cnt)}
      acc += (double)((float)(2 * i + 1) * p.x + (float)(2 * NR - 1 - 2 * i) * p.y);
    }
    if (t == 1023) sh_jnext = (jg >= 0) ? (int)jg : jb + j;
    __syncthreads();
    jb = sh_jnext;
  }
  for (int off = 32; off > 0; off >>= 1) acc += __shfl_down(acc, off);
  if (lane == 0) red16[w] = acc;
  __syncthreads();
  if (t == 0) {
    double s = 0.0;
#pragma unroll
    for (int i = 0; i < 16; ++i) s += red16[i];
    colsum[bid] = s;
  }
}

__global__ __launch_bounds__(1024) void k_final(const double* __restrict__ colsum,
                                                float* __restrict__ out) {
  __shared__ double red16[16];
  int t = threadIdx.x, lane = t & 63, w = t >> 6;
  double v = colsum[t];
  for (int off = 32; off > 0; off >>= 1) v += __shfl_down(v, off);
  if (lane == 0) red16[w] = v;
  __syncthreads();
  if (t == 0) {
    double total = 0.0;
#pragma unroll
    for (int i = 0; i < 16; ++i) total += red16[i];
    double dist = -total / ((double)NR * (double)NC)
                  + 2.0 * (double)NR * log(65538.0) - (double)NR;
    out[0] = (float)dist;
  }
}

extern "C" void kernel_launch(void* const* d_in, const int* in_sizes, int n_in,
                              void* d_out, int out_size, void* d_ws, size_t ws_size,
                              hipStream_t stream) {
  const float* X = (const float*)d_in[0];
  const float* Xh = (const float*)d_in[1];
  float* out = (float*)d_out;

  const size_t NEL = (size_t)NC * NR;  // 64 MiB per buffer
  const size_t B = 65536;              // one plane: 256 cols x 256 bins (u32)
  uint32_t* P0 = (uint32_t*)d_ws;
  uint32_t* P1 = P0 + NEL;
  uint32_t* P2 = P1 + NEL;
  double* colsum = (double*)P1;  // carved from dead P1 after sorts (8 KB)

  dim3 tg(NR / 64, 1, 2);
  k_transpose_key<<<tg, 256, 0, stream>>>(X, Xh, P0, P2);

  // hist region: FH 8B + HZ 2B + HH 6B = 16B u32 = 4 MiB, then tab (524 KB)
  const size_t HSP = 16 * B;
  const size_t TABW = 65537 * 2;  // floats
  uint32_t* nul = nullptr;
  bool fused = ws_size >= (4 * NEL + HSP + TABW) * sizeof(uint32_t);
  if (fused) {
    uint32_t* P3 = P2 + NEL;
    uint32_t* FH = P3 + NEL;
    uint32_t* HZ = FH + 8 * B;
    uint32_t* HH = HZ + 2 * B;
    float2* tab = (float2*)(HH + 6 * B);
    k_allhist<<<769, 1024, 0, stream>>>(P0, P2, FH, HZ, HH, tab);
    k_radix_pass<<<1024, 512, 0, stream>>>(P0, P1, P2, P3, 0,  FH,         HZ,         HH);
    k_radix_pass<<<1024, 512, 0, stream>>>(P1, P0, P3, P2, 8,  FH + 2 * B, HH,         HH + 2 * B);
    k_radix_pass<<<1024, 512, 0, stream>>>(P0, P1, P2, P3, 16, FH + 4 * B, HH + 2 * B, HH + 4 * B);
    k_radix_pass<<<1024, 512, 0, stream>>>(P1, P0, P3, P2, 24, FH + 6 * B, HH + 4 * B, nul);
    k_ad_accum<<<1024, 1024, 0, stream>>>(P0, P2, tab, colsum);
  } else {
    // sequential 3-buffer fallback: per-array passes, grid 512 (arr folds to 0)
    uint32_t* FH = P2 + NEL;
    uint32_t* HZ = FH + 8 * B;
    uint32_t* HH = HZ + 2 * B;
    float2* tab = (float2*)(HH + 6 * B);
    k_allhist<<<769, 1024, 0, stream>>>(P0, P2, FH, HZ, HH, tab);
    for (int arr = 0; arr < 2; ++arr) {
      uint32_t* a = arr ? P2 : P0;
      size_t ao = (size_t)arr * B;
      k_radix_pass<<<512, 512, 0, stream>>>(a,  P1, a,  P1, 0,  FH + ao,         HZ + ao,         HH + ao);
      k_radix_pass<<<512, 512, 0, stream>>>(P1, a,  P1, a,  8,  FH + 2 * B + ao, HH + ao,         HH + 2 * B + ao);
      k_radix_pass<<<512, 512, 0, stream>>>(a,  P1, a,  P1, 16, FH + 4 * B + ao, HH + 2 * B + ao, HH + 4 * B + ao);
      k_radix_pass<<<512, 512, 0, stream>>>(P1, a,  P1, a,  24, FH + 6 * B + ao, HH + 4 * B + ao, nul);
    }
    k_ad_accum<<<1024, 1024, 0, stream>>>(P0, P2, tab, colsum);
  }

  k_final<<<1, 1024, 0, stream>>>(colsum, out);
}